// Round 1
// baseline (310.593 us; speedup 1.0000x reference)
//
#include <hip/hip_runtime.h>
#include <hip/hip_bf16.h>

// GAT layer, B=2 N=4096 F_IN=256 F_OUT=64 H=4.
// k1: x = h@W (fp32), write xT (bf16, [b][f][n]) + elT/erT ([b][h][n] f32)
// k2: fused masked-softmax + PV via mfma_16x16x32_bf16.
//   grid 256 (= B * N/32 i-tiles), 512 thr. wave w: head h=w>>1, ihalf=w&1.
//   Each lane computes its own MFMA A-fragment scores in regs (no P-LDS).
//   adj/xT/er double-buffered in LDS via global_load_lds, XOR-swizzled
//   (linear LDS dest + inverse-swizzled global source, rule #21).

#define NN 4096
#define NH 4

typedef __bf16 bf16x8 __attribute__((ext_vector_type(8)));
typedef unsigned short ushortx8 __attribute__((ext_vector_type(8)));
typedef float f32x4 __attribute__((ext_vector_type(4)));

__device__ __forceinline__ void gload_lds16(const void* g, void* lds) {
  __builtin_amdgcn_global_load_lds(
      (const __attribute__((address_space(1))) void*)g,
      (__attribute__((address_space(3))) void*)lds, 16, 0, 0);
}

__device__ __forceinline__ unsigned short f2bf(float x) {
  __hip_bfloat16 hb = __float2bfloat16(x);
  return __builtin_bit_cast(unsigned short, hb);
}

// ---------------- kernel 1: prep ----------------
__global__ __launch_bounds__(256) void gat_prep(
    const float* __restrict__ hmat, const float* __restrict__ W,
    const float* __restrict__ Wl, const float* __restrict__ Wr,
    unsigned short* __restrict__ xT, float* __restrict__ elT,
    float* __restrict__ erT)
{
  const int t = threadIdx.x;
  const int wv = t >> 6;        // wave 0..3
  const int l  = t & 63;        // lane = output feature f
  const int b  = blockIdx.x >> 6;
  const int i0 = (blockIdx.x & 63) << 6;
  const int r0 = i0 + wv * 16;  // this wave: 16 rows

  float wl[NH], wr[NH];
#pragma unroll
  for (int hh = 0; hh < NH; ++hh) { wl[hh] = Wl[hh*64 + l]; wr[hh] = Wr[hh*64 + l]; }

  float acc[16];
#pragma unroll
  for (int rr = 0; rr < 16; ++rr) acc[rr] = 0.f;

  const float* hbase = hmat + ((size_t)(b*NN + r0)) * 256;
  for (int k4 = 0; k4 < 64; ++k4) {
    float wv4[4];
#pragma unroll
    for (int kk = 0; kk < 4; ++kk) wv4[kk] = W[(k4*4 + kk)*64 + l];
#pragma unroll
    for (int rr = 0; rr < 16; ++rr) {
      const float4 hv = *(const float4*)(hbase + rr*256 + k4*4);
      acc[rr] = fmaf(hv.x, wv4[0], acc[rr]);
      acc[rr] = fmaf(hv.y, wv4[1], acc[rr]);
      acc[rr] = fmaf(hv.z, wv4[2], acc[rr]);
      acc[rr] = fmaf(hv.w, wv4[3], acc[rr]);
    }
  }

#pragma unroll
  for (int rr = 0; rr < 16; ++rr) {
    const int r = r0 + rr;
    xT[((size_t)(b*64 + l))*NN + r] = f2bf(acc[rr]);
#pragma unroll
    for (int hh = 0; hh < NH; ++hh) {
      float ev = acc[rr] * wl[hh];
      float rv = acc[rr] * wr[hh];
#pragma unroll
      for (int s = 1; s < 64; s <<= 1) {
        ev += __shfl_xor(ev, s, 64);
        rv += __shfl_xor(rv, s, 64);
      }
      if (l == 0) {
        elT[((size_t)b*NH + hh)*NN + r] = ev;
        erT[((size_t)b*NH + hh)*NN + r] = rv;
      }
    }
  }
}

// ---------------- kernel 2: fused softmax + PV ----------------
__global__ __launch_bounds__(512, 2) void gat_main(
    const int* __restrict__ adj, const unsigned short* __restrict__ xT,
    const float* __restrict__ elT, const float* __restrict__ erT,
    const float* __restrict__ bias, float* __restrict__ out)
{
  __shared__ __align__(16) int            adj_lds[2][32*64];   // 16 KB
  __shared__ __align__(16) unsigned short xt_lds[2][64*64];    // 16 KB
  __shared__ __align__(16) float          er_lds[2][NH*64];    // 2 KB
  __shared__ __align__(16) float          denom_lds[NH][32];

  const int t = threadIdx.x;
  const int w = t >> 6;               // wave 0..7
  const int l = t & 63;
  const int h = w >> 1;               // head 0..3
  const int ihalf = w & 1;            // which 16-row half of the 32-row tile
  const int b  = blockIdx.x >> 7;
  const int i0 = (blockIdx.x & 127) << 5;

  const int lrow = l & 15;            // MFMA A row / B col / C col
  const int lk   = l >> 4;            // 0..3 (k-group)
  const int i_sc = (ihalf << 4) + lrow;        // tile row 0..31 this lane scores
  const int swzi = (i_sc & 7) << 2;            // int-granular XOR (16B chunks)

  const float el_reg = elT[((size_t)b*NH + h)*NN + i0 + i_sc];

  auto issue_tile = [&](int j0, int bufi) {
    {   // adj: wave w stages rows w*4..w*4+3 (4 x 256 B), 16B-chunk swizzle
      const int ir = (w << 2) + (l >> 4);                // 0..31
      const int c  = (l & 15) ^ (ir & 7);
      gload_lds16(adj + ((size_t)(b*NN + i0 + ir))*NN + j0 + (c << 2),
                  &adj_lds[bufi][w*256]);
    }
    {   // xT: wave w stages f-rows w*8..w*8+7 (8 x 128 B), 16B-chunk swizzle
      const int fr_sub = l >> 3;                          // 0..7
      const int c  = (l & 7) ^ fr_sub;
      gload_lds16(xT + ((size_t)(b*64 + (w<<3) + fr_sub))*NN + j0 + (c << 3),
                  &xt_lds[bufi][w*512]);
    }
    if (w == 0) {  // er tile: [4][64] f32 = 1 KB, broadcast-read, no swizzle
      gload_lds16(erT + ((size_t)b*NH + (l >> 4))*NN + j0 + ((l & 15) << 2),
                  &er_lds[bufi][0]);
    }
  };

  f32x4 acc[4] = {};
  float dsum_acc = 0.f;

  issue_tile(0, 0);

  for (int it = 0; it < NN/64; ++it) {
    const int cur = it & 1;
    asm volatile("s_waitcnt vmcnt(0)" ::: "memory");
    __builtin_amdgcn_s_barrier();
    if (it + 1 < NN/64) issue_tile((it + 1) * 64, cur ^ 1);

    // ---- scores -> A fragments (registers only) ----
    ushortx8 pa[2];
#pragma unroll
    for (int kc = 0; kc < 2; ++kc) {
      const int cbase = kc*32 + (lk << 3);      // j offset within 64-tile
      const int4   aj0 = *(const int4*)  &adj_lds[cur][(i_sc*64 + cbase)     ^ swzi];
      const int4   aj1 = *(const int4*)  &adj_lds[cur][(i_sc*64 + cbase + 4) ^ swzi];
      const float4 er0 = *(const float4*)&er_lds[cur][h*64 + cbase];
      const float4 er1 = *(const float4*)&er_lds[cur][h*64 + cbase + 4];
#define SCORE(A, E, IDX) { \
        float s_ = el_reg + (E); \
        float lr_ = fmaxf(s_, 0.2f * s_); \
        float w_ = (A) ? __expf(lr_) : 0.0f; \
        dsum_acc += w_; \
        pa[kc][IDX] = f2bf(w_); }
      SCORE(aj0.x, er0.x, 0) SCORE(aj0.y, er0.y, 1)
      SCORE(aj0.z, er0.z, 2) SCORE(aj0.w, er0.w, 3)
      SCORE(aj1.x, er1.x, 4) SCORE(aj1.y, er1.y, 5)
      SCORE(aj1.z, er1.z, 6) SCORE(aj1.w, er1.w, 7)
#undef SCORE
    }

    // ---- PV: C[16 i x 64 f] for (h, ihalf) ----
#pragma unroll
    for (int kc = 0; kc < 2; ++kc) {
      const bf16x8 A = __builtin_bit_cast(bf16x8, pa[kc]);
      const int jc = kc*32 + (lk << 3);
#pragma unroll
      for (int fq = 0; fq < 4; ++fq) {
        const int f = (fq << 4) + lrow;
        const int idx = (f*64 + jc) ^ ((f & 7) << 3);
        const bf16x8 B = __builtin_bit_cast(bf16x8, *(const ushortx8*)&xt_lds[cur][idx]);
        acc[fq] = __builtin_amdgcn_mfma_f32_16x16x32_bf16(A, B, acc[fq], 0, 0, 0);
      }
    }
  }

  // ---- denominators: reduce the 4 lanes sharing each row ----
  float rs = dsum_acc;
  rs += __shfl_xor(rs, 16, 64);
  rs += __shfl_xor(rs, 32, 64);
  if (l < 16) denom_lds[h][(ihalf << 4) + l] = rs;
  __syncthreads();

  float inv[4];
#pragma unroll
  for (int r = 0; r < 4; ++r)
    inv[r] = 1.0f / denom_lds[h][(ihalf << 4) + (lk << 2) + r];

#pragma unroll
  for (int fq = 0; fq < 4; ++fq) {
    const int f = (fq << 4) + lrow;
    const float bv = bias[f];
#pragma unroll
    for (int r = 0; r < 4; ++r) {
      const int ir = (ihalf << 4) + (lk << 2) + r;   // C row = (lane>>4)*4 + reg
      float v = acc[fq][r] * inv[r] + bv;
      v = v > 0.f ? v : (__expf(v) - 1.f);
      out[(((size_t)b*NN + i0 + ir)*NH + h)*64 + f] = v;
    }
  }
}

extern "C" void kernel_launch(void* const* d_in, const int* in_sizes, int n_in,
                              void* d_out, int out_size, void* d_ws, size_t ws_size,
                              hipStream_t stream) {
  const int*   adj  = (const int*)d_in[0];
  const float* hmat = (const float*)d_in[1];
  const float* W    = (const float*)d_in[2];
  const float* Wl   = (const float*)d_in[3];
  const float* Wr   = (const float*)d_in[4];
  const float* bias = (const float*)d_in[5];
  float* out = (float*)d_out;

  unsigned short* xT = (unsigned short*)d_ws;                    // 2*64*4096*2 B
  float* elT = (float*)((char*)d_ws + (size_t)2*64*NN*2);        // 2*4*4096 f32
  float* erT = elT + (size_t)2*NH*NN;

  gat_prep<<<128, 256, 0, stream>>>(hmat, W, Wl, Wr, xT, elT, erT);
  gat_main<<<256, 512, 0, stream>>>(adj, xT, elT, erT, bias, out);
}

// Round 3
// 248.557 us; speedup vs baseline: 1.2496x; 1.2496x over previous
//
#include <hip/hip_runtime.h>
#include <hip/hip_bf16.h>

// GAT layer, B=2 N=4096 F_IN=256 F_OUT=64 H=4.
// prep: x = h@W (LDS-staged, no shuffles), xT bf16 [b][f][n], elT/erT pre-scaled by log2e.
// main: i-tile 16 (grid 512), j-tile 128, depth-3 ring + counted vmcnt,
//       scores in regs -> MFMA A-frag, denominator via MFMA with B=ones.

#define NN 4096
#define NH 4
#define JT 128
#define NT (NN / JT)
#define LOG2E 1.4426950408889634f

typedef __bf16 bf16x8 __attribute__((ext_vector_type(8)));
typedef unsigned short ushortx8 __attribute__((ext_vector_type(8)));
typedef unsigned short us4 __attribute__((ext_vector_type(4)));
typedef float f32x4 __attribute__((ext_vector_type(4)));

__device__ __forceinline__ void gload_lds16(const void* g, void* lds) {
  __builtin_amdgcn_global_load_lds(
      (const __attribute__((address_space(1))) void*)g,
      (__attribute__((address_space(3))) void*)lds, 16, 0, 0);
}

__device__ __forceinline__ unsigned short f2bf(float x) {
  __hip_bfloat16 hb = __float2bfloat16(x);
  return __builtin_bit_cast(unsigned short, hb);
}

#if __has_builtin(__builtin_amdgcn_exp2f)
#define EXP2F(x) __builtin_amdgcn_exp2f(x)
#else
#define EXP2F(x) exp2f(x)
#endif

// ---------------- kernel 1: prep ----------------
// grid 512 (b, 16-row tile), block 256 (4 waves). lane = output feature f.
__global__ __launch_bounds__(256, 2) void gat_prep(
    const float* __restrict__ hmat, const float* __restrict__ W,
    const float* __restrict__ Wl, const float* __restrict__ Wr,
    unsigned short* __restrict__ xT, float* __restrict__ elT,
    float* __restrict__ erT)
{
  __shared__ __align__(16) float h_s[16][256];   // 16 KB
  __shared__ float x_s[16][65];                  // padded: bank-conflict-free col reads
  __shared__ float wlr_s[512];                   // Wl (256) | Wr (256)

  const int t  = threadIdx.x;
  const int wv = t >> 6;
  const int l  = t & 63;
  const int b  = blockIdx.x >> 8;
  const int i0 = (blockIdx.x & 255) << 4;

  // stage h tile (coalesced float4) + Wl/Wr
  {
    const float4* hsrc = (const float4*)(hmat + ((size_t)(b * NN + i0)) * 256);
    float4* hdst = (float4*)&h_s[0][0];
#pragma unroll
    for (int u = 0; u < 4; ++u) hdst[t + 256 * u] = hsrc[t + 256 * u];
    wlr_s[t]       = Wl[t];
    wlr_s[256 + t] = Wr[t];
  }
  __syncthreads();

  // phase A: wave wv computes rows wv*4..+4, lane l = feature
  const int row0 = wv << 2;
  float acc[4] = {0.f, 0.f, 0.f, 0.f};
#pragma unroll 4
  for (int k4 = 0; k4 < 64; ++k4) {
    const float w0 = W[(k4 * 4 + 0) * 64 + l];
    const float w1 = W[(k4 * 4 + 1) * 64 + l];
    const float w2 = W[(k4 * 4 + 2) * 64 + l];
    const float w3 = W[(k4 * 4 + 3) * 64 + l];
#pragma unroll
    for (int rr = 0; rr < 4; ++rr) {
      const float4 hv = *(const float4*)&h_s[row0 + rr][k4 * 4];
      acc[rr] = fmaf(hv.x, w0, acc[rr]);
      acc[rr] = fmaf(hv.y, w1, acc[rr]);
      acc[rr] = fmaf(hv.z, w2, acc[rr]);
      acc[rr] = fmaf(hv.w, w3, acc[rr]);
    }
  }
#pragma unroll
  for (int rr = 0; rr < 4; ++rr) x_s[row0 + rr][l] = acc[rr];
  __syncthreads();

  // phase B: el/er (one wave; rows x heads = 64 lanes), pre-scaled by log2e
  if (t < 64) {
    const int row = t >> 2, hh = t & 3;
    float el = 0.f, er = 0.f;
#pragma unroll 8
    for (int f = 0; f < 64; ++f) {
      const float xv = x_s[row][f];
      el = fmaf(xv, wlr_s[hh * 64 + f], el);
      er = fmaf(xv, wlr_s[256 + hh * 64 + f], er);
    }
    elT[((size_t)b * NH + hh) * NN + i0 + row] = el * LOG2E;
    erT[((size_t)b * NH + hh) * NN + i0 + row] = er * LOG2E;
  }

  // xT write: t -> (f = t>>2, quarter q = t&3), 8B per thread
  {
    const int f = t >> 2, q = t & 3;
    us4 pk;
#pragma unroll
    for (int rj = 0; rj < 4; ++rj) pk[rj] = f2bf(x_s[q * 4 + rj][f]);
    *(us4*)&xT[((size_t)(b * 64 + f)) * NN + i0 + q * 4] = pk;
  }
}

// ---------------- kernel 2: fused softmax + PV ----------------
// grid 512 (b, 16-row i-tile), block 256 (4 waves), wave = head.
__global__ __launch_bounds__(256, 2) void gat_main(
    const int* __restrict__ adj, const unsigned short* __restrict__ xT,
    const float* __restrict__ elT, const float* __restrict__ erT,
    const float* __restrict__ bias, float* __restrict__ out)
{
  __shared__ __align__(16) int            adj_lds[3][16 * JT];  // 24 KB
  __shared__ __align__(16) unsigned short xt_lds[3][64 * JT];   // 48 KB
  __shared__ __align__(16) float          er_lds[3][NH * JT];   // 6 KB

  const int t = threadIdx.x;
  const int w = t >> 6;          // wave = head
  const int l = t & 63;
  const int b  = blockIdx.x >> 8;
  const int i0 = (blockIdx.x & 255) << 4;

  const int lrow = l & 15;       // MFMA A row / B col / C col
  const int lk   = l >> 4;       // k-group 0..3

  const float el_reg = elT[((size_t)b * NH + w) * NN + i0 + lrow];

  // stage one j-tile into ring slot s. per-wave loads: w0/w1: 6, w2/w3: 7.
  auto issue_tile = [&](int j0, int s) {
#pragma unroll
    for (int g = 0; g < 2; ++g) {          // adj: 8 KB = 8 gloads, 2/wave
      const int gi  = w * 2 + g;
      const int row = gi * 2 + (l >> 5);
      const int src = ((l & 31) ^ (row & 7)) << 2;   // inverse-swizzled ints
      gload_lds16(adj + ((size_t)(b * NN + i0 + row)) * NN + j0 + src,
                  &adj_lds[s][gi * 256]);
    }
#pragma unroll
    for (int g = 0; g < 4; ++g) {          // xt: 16 KB = 16 gloads, 4/wave
      const int gi = w * 4 + g;
      const int f  = gi * 4 + (l >> 4);
      const int src = ((l & 15) ^ (f & 7)) << 3;     // inverse-swizzled ushorts
      gload_lds16(xT + ((size_t)(b * 64 + f)) * NN + j0 + src,
                  &xt_lds[s][gi * 512]);
    }
    if (w >= 2) {                          // er: 2 KB = 2 gloads (waves 2,3)
      const int h2 = (w - 2) * 2 + (l >> 5);
      gload_lds16(erT + ((size_t)b * NH + h2) * NN + j0 + ((l & 31) << 2),
                  &er_lds[s][(w - 2) * 256]);
    }
  };

  f32x4 acc[4] = {};
  f32x4 accd = {};
  ushortx8 ones_u;
#pragma unroll
  for (int i = 0; i < 8; ++i) ones_u[i] = 0x3F80;    // bf16 1.0
  const bf16x8 onesf = __builtin_bit_cast(bf16x8, ones_u);

  issue_tile(0, 0);
  issue_tile(JT, 1);

  for (int it = 0; it < NT; ++it) {
    const int s = it % 3;
    // counted vmcnt: exactly one newer tile may stay in flight (T4)
    if (it == NT - 1)  asm volatile("s_waitcnt vmcnt(0)" ::: "memory");
    else if (w < 2)    asm volatile("s_waitcnt vmcnt(6)" ::: "memory");
    else               asm volatile("s_waitcnt vmcnt(7)" ::: "memory");
    __builtin_amdgcn_s_barrier();
    __builtin_amdgcn_sched_barrier(0);

    if (it + 2 < NT) issue_tile((it + 2) * JT, (it + 2) % 3);

#pragma unroll
    for (int kc = 0; kc < 4; ++kc) {
      const int cbase = kc * 32 + (lk << 3);   // j-offset (ints) in tile
      const int cq    = cbase >> 2;            // 16B chunk index
      const int4 aj0 = *(const int4*)&adj_lds[s][lrow * JT + ((cq ^ (lrow & 7)) << 2)];
      const int4 aj1 = *(const int4*)&adj_lds[s][lrow * JT + (((cq + 1) ^ (lrow & 7)) << 2)];
      const float4 er0 = *(const float4*)&er_lds[s][w * JT + cbase];
      const float4 er1 = *(const float4*)&er_lds[s][w * JT + cbase + 4];

      ushortx8 pa;
#define SCORE(A_, E_, IDX) { \
        float s_  = el_reg + (E_); \
        float lr_ = fmaxf(s_, 0.2f * s_); \
        float w_  = (A_) ? EXP2F(lr_) : 0.0f; \
        pa[IDX] = f2bf(w_); }
      SCORE(aj0.x, er0.x, 0) SCORE(aj0.y, er0.y, 1)
      SCORE(aj0.z, er0.z, 2) SCORE(aj0.w, er0.w, 3)
      SCORE(aj1.x, er1.x, 4) SCORE(aj1.y, er1.y, 5)
      SCORE(aj1.z, er1.z, 6) SCORE(aj1.w, er1.w, 7)
#undef SCORE

      const bf16x8 A = __builtin_bit_cast(bf16x8, pa);
      accd = __builtin_amdgcn_mfma_f32_16x16x32_bf16(A, onesf, accd, 0, 0, 0);
#pragma unroll
      for (int fq = 0; fq < 4; ++fq) {
        const int f  = (fq << 4) + lrow;
        const int cb = (kc << 2) + lk;       // xt 16B-chunk
        const int idx = f * JT + ((cb ^ (f & 7)) << 3);
        const bf16x8 Bf = __builtin_bit_cast(bf16x8, *(const ushortx8*)&xt_lds[s][idx]);
        acc[fq] = __builtin_amdgcn_mfma_f32_16x16x32_bf16(A, Bf, acc[fq], 0, 0, 0);
      }
    }
  }

  // epilogue: denom is lane-local (rowsum via ones-MFMA), no cross-lane needed
  float inv[4];
#pragma unroll
  for (int r = 0; r < 4; ++r) inv[r] = 1.0f / accd[r];

#pragma unroll
  for (int fq = 0; fq < 4; ++fq) {
    const int f = (fq << 4) + lrow;
    const float bv = bias[f];
#pragma unroll
    for (int r = 0; r < 4; ++r) {
      const int ir = (lk << 2) + r;          // C row = (lane>>4)*4 + reg
      float v = acc[fq][r] * inv[r] + bv;
      v = v > 0.f ? v : (__expf(v) - 1.f);
      out[(((size_t)b * NN + i0 + ir) * NH + w) * 64 + f] = v;
    }
  }
}

extern "C" void kernel_launch(void* const* d_in, const int* in_sizes, int n_in,
                              void* d_out, int out_size, void* d_ws, size_t ws_size,
                              hipStream_t stream) {
  const int*   adj  = (const int*)d_in[0];
  const float* hmat = (const float*)d_in[1];
  const float* W    = (const float*)d_in[2];
  const float* Wl   = (const float*)d_in[3];
  const float* Wr   = (const float*)d_in[4];
  const float* bias = (const float*)d_in[5];
  float* out = (float*)d_out;

  unsigned short* xT = (unsigned short*)d_ws;                    // 2*64*4096*2 B
  float* elT = (float*)((char*)d_ws + (size_t)2 * 64 * NN * 2);  // 2*4*4096 f32
  float* erT = elT + (size_t)2 * NH * NN;

  gat_prep<<<512, 256, 0, stream>>>(hmat, W, Wl, Wr, xT, elT, erT);
  gat_main<<<512, 256, 0, stream>>>(adj, xT, elT, erT, bias, out);
}